// Round 7
// baseline (630.681 us; speedup 1.0000x reference)
//
#include <hip/hip_runtime.h>
#include <hip/hip_bf16.h>

#define B_ 8
#define SPREV 4095
#define S_ 4096
#define E_ 2048
#define H_ 16
#define HD_ 128
#define LOW_ 512
#define NCH 64
#define CHK 64
#define NBLK 512        // 2 blocks/CU x 256 CUs, co-resident via launch_bounds(256,2)
#define SYNC_OFF 11300864

typedef short s8v __attribute__((ext_vector_type(8)));
typedef float f4v __attribute__((ext_vector_type(4)));

__device__ __forceinline__ short f2bf_s(float f) {
  return (short)__bfloat16_as_ushort(__float2bfloat16(f));
}
__device__ __forceinline__ float bf2f(unsigned short h) {
  union { unsigned u; float f; } v; v.u = ((unsigned)h) << 16;
  return v.f;
}

// Device-scope grid barrier (plain launch, graph-capturable). cnt/gen zeroed
// by an in-graph memset before each kernel run. Generation-counted so the
// same pair serves all barriers in one launch.
__device__ __forceinline__ void grid_barrier(int* cnt, int* gen, int nb) {
  __syncthreads();
  if (threadIdx.x == 0) {
    __threadfence();   // flush this block's global writes to coherent point
    int g = __hip_atomic_load(gen, __ATOMIC_RELAXED, __HIP_MEMORY_SCOPE_AGENT);
    int v = __hip_atomic_fetch_add(cnt, 1, __ATOMIC_ACQ_REL, __HIP_MEMORY_SCOPE_AGENT);
    if (v == nb - 1) {
      __hip_atomic_store(cnt, 0, __ATOMIC_RELAXED, __HIP_MEMORY_SCOPE_AGENT);
      __hip_atomic_store(gen, g + 1, __ATOMIC_RELEASE, __HIP_MEMORY_SCOPE_AGENT);
    } else {
      int cur;
      do {
        __builtin_amdgcn_s_sleep(2);
        cur = __hip_atomic_load(gen, __ATOMIC_ACQUIRE, __HIP_MEMORY_SCOPE_AGENT);
      } while (cur == g);
    }
  }
  __syncthreads();
}

// out[b][col] += sum over 32 k's; 128 cols per task, 2 k-halves (t>>7).
__device__ __forceinline__ void matvec_body(
    const float* __restrict__ xv, int K, const float* __restrict__ W,
    float* __restrict__ o, int N, int colbase, int ky, int t)
{
  int col = colbase + (t & 127);
  int k0 = ky * 64 + (t >> 7) * 32;
  float acc[B_];
  #pragma unroll
  for (int b = 0; b < B_; ++b) acc[b] = 0.f;
  const float* Wp = W + (size_t)k0 * N + col;
  #pragma unroll 8
  for (int k = 0; k < 32; ++k) {
    float wv = Wp[(size_t)k * N];
    #pragma unroll
    for (int b = 0; b < B_; ++b)
      acc[b] = fmaf(xv[b * K + k0 + k], wv, acc[b]);   // uniform -> s_load
  }
  #pragma unroll
  for (int b = 0; b < B_; ++b) atomicAdd(&o[b * N + col], acc[b]);
}

__global__ __launch_bounds__(256, 2) void mega_kernel(
    const float* __restrict__ x, const float* __restrict__ ckvc,
    const float* __restrict__ krc, const float* __restrict__ Wdq,
    const float* __restrict__ Wuq, const float* __restrict__ Wqr,
    const float* __restrict__ Wdkv, const float* __restrict__ Wkr,
    const float* __restrict__ FU, const float* __restrict__ Wo,
    float* __restrict__ out, char* __restrict__ ws)
{
  float* Cq      = (float*)(ws + 0);
  float* Qc      = (float*)(ws + 65536);
  float* qr_pre  = (float*)(ws + 131072);
  float* ckvn    = (float*)(ws + 135168);
  float* krn     = (float*)(ws + 151552);
  float* wl      = (float*)(ws + 155648);
  float* o_heads = (float*)(ws + 417792);
  unsigned short* qeff = (unsigned short*)(ws + 483328);
  float* score_r = (float*)(ws + 614400);
  float* m_part  = (float*)(ws + 745472);
  float* l_part  = (float*)(ws + 778240);
  unsigned short* accp = (unsigned short*)(ws + 811008);
  float2* tab2   = (float2*)(ws + 9199616);
  int* cnt       = (int*)(ws + SYNC_OFF);
  int* gen       = (int*)(ws + SYNC_OFF + 64);

  const int nb = gridDim.x;
  const int blk = blockIdx.x;
  const int t = threadIdx.x;

  __shared__ float qs[HD_];
  __shared__ float qr_sh[128];
  __shared__ float S_lds[16 * 64];
  __shared__ unsigned short P_lds[16 * 64];
  __shared__ float wli[8];
  __shared__ float wsh[64];

  // ---- S0: zero atomic targets + rope table tab2[s][j] ----
  for (int i = blk * 256 + t; i < 262144; i += nb * 256) {
    if (i < 120832) ((float*)ws)[i] = 0.f;        // Cq,Qc,qr_pre,ckvn,krn,wl,o_heads
    else if (i < 137216) out[i - 120832] = 0.f;
    int s = i >> 6, j = i & 63;
    float invf = powf(10000.0f, -(float)j * (1.0f / 64.0f));
    float sn, cs; sincosf((float)s * invf, &sn, &cs);
    tab2[i] = make_float2(cs, sn);
  }
  grid_barrier(cnt, gen, nb);

  // ---- S1: Cq = x@Wdq ; ckvn = x@Wdkv ; krn = x@Wkr ----
  for (int task = blk; task < 672; task += nb) {
    int cb = task % 21, ky = task / 21;
    if (cb < 16)      matvec_body(x, E_, Wdq,  Cq,   E_,   cb << 7,        ky, t);
    else if (cb < 20) matvec_body(x, E_, Wdkv, ckvn, LOW_, (cb - 16) << 7, ky, t);
    else              matvec_body(x, E_, Wkr,  krn,  HD_,  0,              ky, t);
  }
  grid_barrier(cnt, gen, nb);

  // ---- S2: Qc = Cq@Wuq ; qr_pre = Cq@Wqr ----
  for (int task = blk; task < 544; task += nb) {
    int cb = task % 17, ky = task / 17;
    if (cb < 16) matvec_body(Cq, E_, Wuq, Qc,     E_,  cb << 7, ky, t);
    else         matvec_body(Cq, E_, Wqr, qr_pre, HD_, 0,       ky, t);
  }
  grid_barrier(cnt, gen, nb);

  // ---- S3: qeff (bx<32: h=bx>>1, half l's) + rope (bx>=32: 128 s each) ----
  for (int task = blk; task < 512; task += nb) {
    int bx = task & 63, b = task >> 6;
    int g = t >> 4, li = t & 15;
    if (bx < 32) {
      int h = bx >> 1, ph = (bx & 1) * 16;
      __syncthreads();
      if (t < 128) qs[t] = Qc[b * E_ + h * HD_ + t];
      __syncthreads();
      f4v q0 = *(const f4v*)&qs[li * 8];
      f4v q1 = *(const f4v*)&qs[li * 8 + 4];
      #pragma unroll 4
      for (int p = ph; p < ph + 16; ++p) {
        int l = p * 16 + g;
        const f4v* w4 = (const f4v*)(FU + (size_t)l * (2 * E_) + h * HD_ + li * 8);
        f4v w0 = w4[0], w1 = w4[1];
        float a = w0[0]*q0[0] + w0[1]*q0[1] + w0[2]*q0[2] + w0[3]*q0[3]
                + w1[0]*q1[0] + w1[1]*q1[1] + w1[2]*q1[2] + w1[3]*q1[3];
        a += __shfl_xor(a, 1); a += __shfl_xor(a, 2);
        a += __shfl_xor(a, 4); a += __shfl_xor(a, 8);
        if (li == 0) qeff[(size_t)(b * H_ + h) * LOW_ + l] = (unsigned short)f2bf_s(a);
      }
    } else {
      int s_base = (bx - 32) * 128;
      __syncthreads();
      if (t < 64) {
        float invf = powf(10000.0f, -(float)t * (1.0f / 64.0f));
        float x1 = qr_pre[b * HD_ + t], x2 = qr_pre[b * HD_ + 64 + t];
        float sn, cs; sincosf(4095.0f * invf, &sn, &cs);
        qr_sh[t]      = x1 * cs - x2 * sn;
        qr_sh[64 + t] = x1 * sn + x2 * cs;
      }
      __syncthreads();
      f4v qa = *(const f4v*)&qr_sh[li * 4];
      f4v qb = *(const f4v*)&qr_sh[64 + li * 4];
      #pragma unroll 2
      for (int p = 0; p < 8; ++p) {
        int s = s_base + p * 16 + g;
        const float* krp = (s == S_ - 1) ? (krn + b * HD_)
                                         : (krc + ((size_t)b * SPREV + s) * HD_);
        f4v x1 = *(const f4v*)&krp[li * 4];
        f4v x2 = *(const f4v*)&krp[64 + li * 4];
        const float2* tp = &tab2[(size_t)s * 64 + li * 4];
        float dot = 0.f;
        #pragma unroll
        for (int q = 0; q < 4; ++q) {
          float2 cs2 = tp[q];
          dot += qa[q] * (x1[q] * cs2.x - x2[q] * cs2.y)
               + qb[q] * (x1[q] * cs2.y + x2[q] * cs2.x);
        }
        dot += __shfl_xor(dot, 1); dot += __shfl_xor(dot, 2);
        dot += __shfl_xor(dot, 4); dot += __shfl_xor(dot, 8);
        if (li == 0) score_r[b * S_ + s] = dot;
      }
    }
  }
  grid_barrier(cnt, gen, nb);

  // ---- S4: flash-decode attention, one (b, chunk) per task ----
  for (int task = blk; task < 512; task += nb) {
    int chunk = task & 63, b = task >> 6;
    int w = t >> 6, lane = t & 63;
    int kg = lane >> 4, l16 = lane & 15;
    __syncthreads();
    { // phase A
      int s_loc = w * 16 + l16;
      int s = chunk * CHK + s_loc;
      const float* crow = (s == S_ - 1) ? (ckvn + b * LOW_)
                                        : (ckvc + ((size_t)b * SPREV + s) * LOW_);
      f4v acc = {0.f, 0.f, 0.f, 0.f};
      const s8v* qf = (const s8v*)(qeff + (size_t)(b * H_ + l16) * LOW_);
      #pragma unroll
      for (int kt = 0; kt < 16; ++kt) {
        s8v a = qf[kt * 4 + kg];
        const float* cp = crow + kt * 32 + kg * 8;
        f4v c0 = *(const f4v*)cp;
        f4v c1 = *(const f4v*)(cp + 4);
        s8v bv;
        bv[0]=f2bf_s(c0[0]); bv[1]=f2bf_s(c0[1]); bv[2]=f2bf_s(c0[2]); bv[3]=f2bf_s(c0[3]);
        bv[4]=f2bf_s(c1[0]); bv[5]=f2bf_s(c1[1]); bv[6]=f2bf_s(c1[2]); bv[7]=f2bf_s(c1[3]);
        acc = __builtin_amdgcn_mfma_f32_16x16x32_bf16(a, bv, acc, 0, 0, 0);
      }
      #pragma unroll
      for (int r = 0; r < 4; ++r) {
        int h = kg * 4 + r;
        S_lds[h * 64 + (s_loc ^ ((h & 7) << 2))] = acc[r];
      }
    }
    __syncthreads();
    if (w == 0) { // phase B
      int h = l16, part = kg;
      float v[16];
      #pragma unroll
      for (int jj = 0; jj < 4; ++jj) {
        int sb = part * 16 + jj * 4;
        f4v sv = *(const f4v*)&S_lds[h * 64 + (sb ^ ((h & 7) << 2))];
        f4v rv = *(const f4v*)&score_r[b * S_ + chunk * CHK + sb];
        #pragma unroll
        for (int q = 0; q < 4; ++q) v[jj * 4 + q] = (sv[q] + rv[q]) * 0.0625f;
      }
      float m = v[0];
      #pragma unroll
      for (int j = 1; j < 16; ++j) m = fmaxf(m, v[j]);
      m = fmaxf(m, __shfl_xor(m, 16));
      m = fmaxf(m, __shfl_xor(m, 32));
      float lsum = 0.f;
      #pragma unroll
      for (int j = 0; j < 16; ++j) { v[j] = expf(v[j] - m); lsum += v[j]; }
      lsum += __shfl_xor(lsum, 16);
      lsum += __shfl_xor(lsum, 32);
      #pragma unroll
      for (int jj = 0; jj < 8; ++jj) {
        int sb = part * 16 + jj * 2;
        unsigned pk = (unsigned)(unsigned short)f2bf_s(v[jj*2]) |
                      ((unsigned)(unsigned short)f2bf_s(v[jj*2+1]) << 16);
        *(unsigned*)&P_lds[h * 64 + (sb ^ ((h & 7) << 3))] = pk;
      }
      if (part == 0) {
        int idx = (b * NCH + chunk) * H_ + h;
        m_part[idx] = m;
        l_part[idx] = lsum;
      }
    }
    __syncthreads();
    { // phase C
      s8v pa[2];
      const float* rp[2][8];
      #pragma unroll
      for (int kt = 0; kt < 2; ++kt) {
        int so = kt * 32 + kg * 8;
        pa[kt] = *(const s8v*)&P_lds[l16 * 64 + (so ^ ((l16 & 7) << 3))];
        #pragma unroll
        for (int i = 0; i < 8; ++i) {
          int s = chunk * CHK + so + i;
          rp[kt][i] = (s == S_ - 1) ? (ckvn + b * LOW_)
                                    : (ckvc + ((size_t)b * SPREV + s) * LOW_);
        }
      }
      f4v oa[8];
      #pragma unroll
      for (int nt = 0; nt < 8; ++nt) oa[nt] = {0.f, 0.f, 0.f, 0.f};
      #pragma unroll
      for (int nt = 0; nt < 8; ++nt) {
        int l = w * 128 + nt * 16 + l16;
        #pragma unroll
        for (int kt = 0; kt < 2; ++kt) {
          s8v bv;
          #pragma unroll
          for (int i = 0; i < 8; ++i) bv[i] = (short)f2bf_s(rp[kt][i][l]);
          oa[nt] = __builtin_amdgcn_mfma_f32_16x16x32_bf16(pa[kt], bv, oa[nt], 0, 0, 0);
        }
      }
      size_t base = (size_t)(b * NCH + chunk) * H_;
      #pragma unroll
      for (int nt = 0; nt < 8; ++nt) {
        int l = w * 128 + nt * 16 + l16;
        #pragma unroll
        for (int r = 0; r < 4; ++r) {
          int h = kg * 4 + r;
          accp[(base + h) * LOW_ + l] = (unsigned short)f2bf_s(oa[nt][r]);
        }
      }
    }
  }
  grid_barrier(cnt, gen, nb);

  // ---- S5: combine chunk partials into wl (f32 atomics) ----
  for (int task = blk; task < 1024; task += nb) {
    int h = task & 15, b = (task >> 4) & 7, cz = task >> 7;
    __syncthreads();
    if (t < 64) {
      float mc = m_part[(b * NCH + t) * H_ + h];
      float M = mc;
      #pragma unroll
      for (int d = 1; d < 64; d <<= 1) M = fmaxf(M, __shfl_xor(M, d));
      float wc = expf(mc - M);
      float L = l_part[(b * NCH + t) * H_ + h] * wc;
      #pragma unroll
      for (int d = 1; d < 64; d <<= 1) L += __shfl_xor(L, d);
      int rel = t - cz * 8;
      if (rel >= 0 && rel < 8) wli[rel] = wc / L;
    }
    __syncthreads();
    if (t < 128) {
      int l0 = t * 4;
      float a0 = 0.f, a1 = 0.f, a2 = 0.f, a3 = 0.f;
      const unsigned short* ap =
          accp + ((size_t)(b * NCH + cz * 8) * H_ + h) * LOW_ + l0;
      #pragma unroll
      for (int c = 0; c < 8; ++c) {
        uint2 pk = *(const uint2*)(ap + (size_t)c * H_ * LOW_);
        float wc = wli[c];
        a0 = fmaf(bf2f((unsigned short)(pk.x & 0xffffu)), wc, a0);
        a1 = fmaf(bf2f((unsigned short)(pk.x >> 16)),     wc, a1);
        a2 = fmaf(bf2f((unsigned short)(pk.y & 0xffffu)), wc, a2);
        a3 = fmaf(bf2f((unsigned short)(pk.y >> 16)),     wc, a3);
      }
      float* wp = wl + (size_t)(b * H_ + h) * LOW_ + l0;
      atomicAdd(wp, a0); atomicAdd(wp + 1, a1);
      atomicAdd(wp + 2, a2); atomicAdd(wp + 3, a3);
    }
  }
  grid_barrier(cnt, gen, nb);

  // ---- S6: project wl through FU V-half into o_heads ----
  for (int task = blk; task < 1024; task += nb) {
    int h = task & 15, b = (task >> 4) & 7, lz = task >> 7;
    __syncthreads();
    if (t < 64) wsh[t] = wl[(b * H_ + h) * LOW_ + lz * 64 + t];
    __syncthreads();
    if (t < 128) {
      int d = t;
      float a = 0.f;
      const float* fp = FU + (size_t)(lz * 64) * (2 * E_) + E_ + h * HD_ + d;
      #pragma unroll 4
      for (int l = 0; l < 64; ++l)
        a = fmaf(wsh[l], fp[(size_t)l * (2 * E_)], a);
      atomicAdd(&o_heads[(b * H_ + h) * HD_ + d], a);
    }
  }
  grid_barrier(cnt, gen, nb);

  // ---- S7: out = o_heads @ Wo ----
  for (int task = blk; task < 512; task += nb) {
    int cb = task & 15, ky = task >> 4;
    matvec_body(o_heads, E_, Wo, out, E_, cb << 7, ky, t);
  }
}

extern "C" void kernel_launch(void* const* d_in, const int* in_sizes, int n_in,
                              void* d_out, int out_size, void* d_ws, size_t ws_size,
                              hipStream_t stream)
{
  const float* x    = (const float*)d_in[0];
  const float* ckvc = (const float*)d_in[1];
  const float* krc  = (const float*)d_in[2];
  const float* Wdq  = (const float*)d_in[3];
  const float* Wuq  = (const float*)d_in[4];
  const float* Wqr  = (const float*)d_in[5];
  const float* Wdkv = (const float*)d_in[6];
  const float* Wkr  = (const float*)d_in[7];
  const float* FU   = (const float*)d_in[8];
  const float* Wo   = (const float*)d_in[9];
  float* out = (float*)d_out;
  char* ws = (char*)d_ws;

  // Zero the grid-barrier state (cnt, gen) each call; everything else the
  // kernel zeroes itself in S0.
  hipMemsetAsync(ws + SYNC_OFF, 0, 128, stream);
  mega_kernel<<<dim3(NBLK), dim3(256), 0, stream>>>(
      x, ckvc, krc, Wdq, Wuq, Wqr, Wdkv, Wkr, FU, Wo, out, ws);
}

// Round 9
// 350.600 us; speedup vs baseline: 1.7989x; 1.7989x over previous
//
#include <hip/hip_runtime.h>
#include <hip/hip_bf16.h>

#define B_ 8
#define SPREV 4095
#define S_ 4096
#define E_ 2048
#define H_ 16
#define HD_ 128
#define LOW_ 512
#define NCH 64
#define CHK 64
#define NBLK 512        // 2 blocks/CU x 256 CUs, co-resident via launch_bounds(256,2)
#define SYNC_OFF 11300864

typedef short s8v __attribute__((ext_vector_type(8)));
typedef float f4v __attribute__((ext_vector_type(4)));

__device__ __forceinline__ short f2bf_s(float f) {
  return (short)__bfloat16_as_ushort(__float2bfloat16(f));
}
__device__ __forceinline__ float bf2f(unsigned short h) {
  union { unsigned u; float f; } v; v.u = ((unsigned)h) << 16;
  return v.f;
}

// Monotonic grid barrier. Arrival: release-fence + relaxed fetch_add (agent
// scope -> coherent point). Wait: RELAXED polls (no per-poll cache
// invalidation), then ONE acquire fence post-spin. target = barrier_idx*NBLK;
// cnt never resets within a launch (no reuse race). Spin is BOUNDED so a
// logic bug degrades to a wrong answer, never a GPU hang.
__device__ __forceinline__ void grid_barrier(int* cnt, int target) {
  __syncthreads();
  if (threadIdx.x == 0) {
    __builtin_amdgcn_fence(__ATOMIC_RELEASE, "agent");   // flush my writes
    __hip_atomic_fetch_add(cnt, 1, __ATOMIC_RELAXED, __HIP_MEMORY_SCOPE_AGENT);
    for (int spin = 0; spin < 10000000; ++spin) {
      if (__hip_atomic_load(cnt, __ATOMIC_RELAXED, __HIP_MEMORY_SCOPE_AGENT) >= target)
        break;
      __builtin_amdgcn_s_sleep(4);
    }
    __builtin_amdgcn_fence(__ATOMIC_ACQUIRE, "agent");   // one inv, post-spin
  }
  __syncthreads();
}

// out[b][col] += sum over 32 k's; 128 cols per task, 2 k-halves (t>>7).
__device__ __forceinline__ void matvec_body(
    const float* __restrict__ xv, int K, const float* __restrict__ W,
    float* __restrict__ o, int N, int colbase, int ky, int t)
{
  int col = colbase + (t & 127);
  int k0 = ky * 64 + (t >> 7) * 32;
  float acc[B_];
  #pragma unroll
  for (int b = 0; b < B_; ++b) acc[b] = 0.f;
  const float* Wp = W + (size_t)k0 * N + col;
  #pragma unroll 8
  for (int k = 0; k < 32; ++k) {
    float wv = Wp[(size_t)k * N];
    #pragma unroll
    for (int b = 0; b < B_; ++b)
      acc[b] = fmaf(xv[b * K + k0 + k], wv, acc[b]);   // uniform -> s_load
  }
  #pragma unroll
  for (int b = 0; b < B_; ++b) atomicAdd(&o[b * N + col], acc[b]);
}

__global__ __launch_bounds__(256, 2) void mega_kernel(
    const float* __restrict__ x, const float* __restrict__ ckvc,
    const float* __restrict__ krc, const float* __restrict__ Wdq,
    const float* __restrict__ Wuq, const float* __restrict__ Wqr,
    const float* __restrict__ Wdkv, const float* __restrict__ Wkr,
    const float* __restrict__ FU, const float* __restrict__ Wo,
    float* __restrict__ out, char* __restrict__ ws)
{
  float* Cq      = (float*)(ws + 0);
  float* Qc      = (float*)(ws + 65536);
  float* qr_pre  = (float*)(ws + 131072);
  float* ckvn    = (float*)(ws + 135168);
  float* krn     = (float*)(ws + 151552);
  float* wl      = (float*)(ws + 155648);
  float* o_heads = (float*)(ws + 417792);
  unsigned short* qeff = (unsigned short*)(ws + 483328);
  float* score_r = (float*)(ws + 614400);
  float* m_part  = (float*)(ws + 745472);
  float* l_part  = (float*)(ws + 778240);
  unsigned short* accp = (unsigned short*)(ws + 811008);
  float2* tab2   = (float2*)(ws + 9199616);
  int* cnt       = (int*)(ws + SYNC_OFF);

  const int nb = NBLK;
  const int blk = blockIdx.x;
  const int t = threadIdx.x;

  __shared__ float qs[HD_];
  __shared__ float qr_sh[128];
  __shared__ float S_lds[16 * 64];
  __shared__ unsigned short P_lds[16 * 64];
  __shared__ float wli[8];
  __shared__ float wsh[64];

  // ---- S0: zero atomic targets + rope table tab2[s][j] ----
  for (int i = blk * 256 + t; i < 262144; i += nb * 256) {
    if (i < 120832) ((float*)ws)[i] = 0.f;        // Cq,Qc,qr_pre,ckvn,krn,wl,o_heads
    else if (i < 137216) out[i - 120832] = 0.f;
    int s = i >> 6, j = i & 63;
    float invf = powf(10000.0f, -(float)j * (1.0f / 64.0f));
    float sn, cs; sincosf((float)s * invf, &sn, &cs);
    tab2[i] = make_float2(cs, sn);
  }
  grid_barrier(cnt, 1 * NBLK);

  // ---- S1: Cq = x@Wdq ; ckvn = x@Wdkv ; krn = x@Wkr ----
  for (int task = blk; task < 672; task += nb) {
    int cb = task % 21, ky = task / 21;
    if (cb < 16)      matvec_body(x, E_, Wdq,  Cq,   E_,   cb << 7,        ky, t);
    else if (cb < 20) matvec_body(x, E_, Wdkv, ckvn, LOW_, (cb - 16) << 7, ky, t);
    else              matvec_body(x, E_, Wkr,  krn,  HD_,  0,              ky, t);
  }
  grid_barrier(cnt, 2 * NBLK);

  // ---- S2: Qc = Cq@Wuq ; qr_pre = Cq@Wqr ----
  for (int task = blk; task < 544; task += nb) {
    int cb = task % 17, ky = task / 17;
    if (cb < 16) matvec_body(Cq, E_, Wuq, Qc,     E_,  cb << 7, ky, t);
    else         matvec_body(Cq, E_, Wqr, qr_pre, HD_, 0,       ky, t);
  }
  grid_barrier(cnt, 3 * NBLK);

  // ---- S3: qeff (bx<32: h=bx>>1, half l's) + rope (bx>=32: 128 s each) ----
  for (int task = blk; task < 512; task += nb) {
    int bx = task & 63, b = task >> 6;
    int g = t >> 4, li = t & 15;
    if (bx < 32) {
      int h = bx >> 1, ph = (bx & 1) * 16;
      __syncthreads();
      if (t < 128) qs[t] = Qc[b * E_ + h * HD_ + t];
      __syncthreads();
      f4v q0 = *(const f4v*)&qs[li * 8];
      f4v q1 = *(const f4v*)&qs[li * 8 + 4];
      #pragma unroll 4
      for (int p = ph; p < ph + 16; ++p) {
        int l = p * 16 + g;
        const f4v* w4 = (const f4v*)(FU + (size_t)l * (2 * E_) + h * HD_ + li * 8);
        f4v w0 = w4[0], w1 = w4[1];
        float a = w0[0]*q0[0] + w0[1]*q0[1] + w0[2]*q0[2] + w0[3]*q0[3]
                + w1[0]*q1[0] + w1[1]*q1[1] + w1[2]*q1[2] + w1[3]*q1[3];
        a += __shfl_xor(a, 1); a += __shfl_xor(a, 2);
        a += __shfl_xor(a, 4); a += __shfl_xor(a, 8);
        if (li == 0) qeff[(size_t)(b * H_ + h) * LOW_ + l] = (unsigned short)f2bf_s(a);
      }
    } else {
      int s_base = (bx - 32) * 128;
      __syncthreads();
      if (t < 64) {
        float invf = powf(10000.0f, -(float)t * (1.0f / 64.0f));
        float x1 = qr_pre[b * HD_ + t], x2 = qr_pre[b * HD_ + 64 + t];
        float sn, cs; sincosf(4095.0f * invf, &sn, &cs);
        qr_sh[t]      = x1 * cs - x2 * sn;
        qr_sh[64 + t] = x1 * sn + x2 * cs;
      }
      __syncthreads();
      f4v qa = *(const f4v*)&qr_sh[li * 4];
      f4v qb = *(const f4v*)&qr_sh[64 + li * 4];
      #pragma unroll 2
      for (int p = 0; p < 8; ++p) {
        int s = s_base + p * 16 + g;
        const float* krp = (s == S_ - 1) ? (krn + b * HD_)
                                         : (krc + ((size_t)b * SPREV + s) * HD_);
        f4v x1 = *(const f4v*)&krp[li * 4];
        f4v x2 = *(const f4v*)&krp[64 + li * 4];
        const float2* tp = &tab2[(size_t)s * 64 + li * 4];
        float dot = 0.f;
        #pragma unroll
        for (int q = 0; q < 4; ++q) {
          float2 cs2 = tp[q];
          dot += qa[q] * (x1[q] * cs2.x - x2[q] * cs2.y)
               + qb[q] * (x1[q] * cs2.y + x2[q] * cs2.x);
        }
        dot += __shfl_xor(dot, 1); dot += __shfl_xor(dot, 2);
        dot += __shfl_xor(dot, 4); dot += __shfl_xor(dot, 8);
        if (li == 0) score_r[b * S_ + s] = dot;
      }
    }
  }
  grid_barrier(cnt, 4 * NBLK);

  // ---- S4: flash-decode attention, one (b, chunk) per task ----
  for (int task = blk; task < 512; task += nb) {
    int chunk = task & 63, b = task >> 6;
    int w = t >> 6, lane = t & 63;
    int kg = lane >> 4, l16 = lane & 15;
    __syncthreads();
    { // phase A
      int s_loc = w * 16 + l16;
      int s = chunk * CHK + s_loc;
      const float* crow = (s == S_ - 1) ? (ckvn + b * LOW_)
                                        : (ckvc + ((size_t)b * SPREV + s) * LOW_);
      f4v acc = {0.f, 0.f, 0.f, 0.f};
      const s8v* qf = (const s8v*)(qeff + (size_t)(b * H_ + l16) * LOW_);
      #pragma unroll
      for (int kt = 0; kt < 16; ++kt) {
        s8v a = qf[kt * 4 + kg];
        const float* cp = crow + kt * 32 + kg * 8;
        f4v c0 = *(const f4v*)cp;
        f4v c1 = *(const f4v*)(cp + 4);
        s8v bv;
        bv[0]=f2bf_s(c0[0]); bv[1]=f2bf_s(c0[1]); bv[2]=f2bf_s(c0[2]); bv[3]=f2bf_s(c0[3]);
        bv[4]=f2bf_s(c1[0]); bv[5]=f2bf_s(c1[1]); bv[6]=f2bf_s(c1[2]); bv[7]=f2bf_s(c1[3]);
        acc = __builtin_amdgcn_mfma_f32_16x16x32_bf16(a, bv, acc, 0, 0, 0);
      }
      #pragma unroll
      for (int r = 0; r < 4; ++r) {
        int h = kg * 4 + r;
        S_lds[h * 64 + (s_loc ^ ((h & 7) << 2))] = acc[r];
      }
    }
    __syncthreads();
    if (w == 0) { // phase B
      int h = l16, part = kg;
      float v[16];
      #pragma unroll
      for (int jj = 0; jj < 4; ++jj) {
        int sb = part * 16 + jj * 4;
        f4v sv = *(const f4v*)&S_lds[h * 64 + (sb ^ ((h & 7) << 2))];
        f4v rv = *(const f4v*)&score_r[b * S_ + chunk * CHK + sb];
        #pragma unroll
        for (int q = 0; q < 4; ++q) v[jj * 4 + q] = (sv[q] + rv[q]) * 0.0625f;
      }
      float m = v[0];
      #pragma unroll
      for (int j = 1; j < 16; ++j) m = fmaxf(m, v[j]);
      m = fmaxf(m, __shfl_xor(m, 16));
      m = fmaxf(m, __shfl_xor(m, 32));
      float lsum = 0.f;
      #pragma unroll
      for (int j = 0; j < 16; ++j) { v[j] = expf(v[j] - m); lsum += v[j]; }
      lsum += __shfl_xor(lsum, 16);
      lsum += __shfl_xor(lsum, 32);
      #pragma unroll
      for (int jj = 0; jj < 8; ++jj) {
        int sb = part * 16 + jj * 2;
        unsigned pk = (unsigned)(unsigned short)f2bf_s(v[jj*2]) |
                      ((unsigned)(unsigned short)f2bf_s(v[jj*2+1]) << 16);
        *(unsigned*)&P_lds[h * 64 + (sb ^ ((h & 7) << 3))] = pk;
      }
      if (part == 0) {
        int idx = (b * NCH + chunk) * H_ + h;
        m_part[idx] = m;
        l_part[idx] = lsum;
      }
    }
    __syncthreads();
    { // phase C
      s8v pa[2];
      const float* rp[2][8];
      #pragma unroll
      for (int kt = 0; kt < 2; ++kt) {
        int so = kt * 32 + kg * 8;
        pa[kt] = *(const s8v*)&P_lds[l16 * 64 + (so ^ ((l16 & 7) << 3))];
        #pragma unroll
        for (int i = 0; i < 8; ++i) {
          int s = chunk * CHK + so + i;
          rp[kt][i] = (s == S_ - 1) ? (ckvn + b * LOW_)
                                    : (ckvc + ((size_t)b * SPREV + s) * LOW_);
        }
      }
      f4v oa[8];
      #pragma unroll
      for (int nt = 0; nt < 8; ++nt) oa[nt] = {0.f, 0.f, 0.f, 0.f};
      #pragma unroll
      for (int nt = 0; nt < 8; ++nt) {
        int l = w * 128 + nt * 16 + l16;
        #pragma unroll
        for (int kt = 0; kt < 2; ++kt) {
          s8v bv;
          #pragma unroll
          for (int i = 0; i < 8; ++i) bv[i] = (short)f2bf_s(rp[kt][i][l]);
          oa[nt] = __builtin_amdgcn_mfma_f32_16x16x32_bf16(pa[kt], bv, oa[nt], 0, 0, 0);
        }
      }
      size_t base = (size_t)(b * NCH + chunk) * H_;
      #pragma unroll
      for (int nt = 0; nt < 8; ++nt) {
        int l = w * 128 + nt * 16 + l16;
        #pragma unroll
        for (int r = 0; r < 4; ++r) {
          int h = kg * 4 + r;
          accp[(base + h) * LOW_ + l] = (unsigned short)f2bf_s(oa[nt][r]);
        }
      }
    }
  }
  grid_barrier(cnt, 5 * NBLK);

  // ---- S5: combine chunk partials into wl (f32 atomics) ----
  for (int task = blk; task < 1024; task += nb) {
    int h = task & 15, b = (task >> 4) & 7, cz = task >> 7;
    __syncthreads();
    if (t < 64) {
      float mc = m_part[(b * NCH + t) * H_ + h];
      float M = mc;
      #pragma unroll
      for (int d = 1; d < 64; d <<= 1) M = fmaxf(M, __shfl_xor(M, d));
      float wc = expf(mc - M);
      float L = l_part[(b * NCH + t) * H_ + h] * wc;
      #pragma unroll
      for (int d = 1; d < 64; d <<= 1) L += __shfl_xor(L, d);
      int rel = t - cz * 8;
      if (rel >= 0 && rel < 8) wli[rel] = wc / L;
    }
    __syncthreads();
    if (t < 128) {
      int l0 = t * 4;
      float a0 = 0.f, a1 = 0.f, a2 = 0.f, a3 = 0.f;
      const unsigned short* ap =
          accp + ((size_t)(b * NCH + cz * 8) * H_ + h) * LOW_ + l0;
      #pragma unroll
      for (int c = 0; c < 8; ++c) {
        uint2 pk = *(const uint2*)(ap + (size_t)c * H_ * LOW_);
        float wc = wli[c];
        a0 = fmaf(bf2f((unsigned short)(pk.x & 0xffffu)), wc, a0);
        a1 = fmaf(bf2f((unsigned short)(pk.x >> 16)),     wc, a1);
        a2 = fmaf(bf2f((unsigned short)(pk.y & 0xffffu)), wc, a2);
        a3 = fmaf(bf2f((unsigned short)(pk.y >> 16)),     wc, a3);
      }
      float* wp = wl + (size_t)(b * H_ + h) * LOW_ + l0;
      atomicAdd(wp, a0); atomicAdd(wp + 1, a1);
      atomicAdd(wp + 2, a2); atomicAdd(wp + 3, a3);
    }
  }
  grid_barrier(cnt, 6 * NBLK);

  // ---- S6: project wl through FU V-half into o_heads ----
  for (int task = blk; task < 1024; task += nb) {
    int h = task & 15, b = (task >> 4) & 7, lz = task >> 7;
    __syncthreads();
    if (t < 64) wsh[t] = wl[(b * H_ + h) * LOW_ + lz * 64 + t];
    __syncthreads();
    if (t < 128) {
      int d = t;
      float a = 0.f;
      const float* fp = FU + (size_t)(lz * 64) * (2 * E_) + E_ + h * HD_ + d;
      #pragma unroll 4
      for (int l = 0; l < 64; ++l)
        a = fmaf(wsh[l], fp[(size_t)l * (2 * E_)], a);
      atomicAdd(&o_heads[(b * H_ + h) * HD_ + d], a);
    }
  }
  grid_barrier(cnt, 7 * NBLK);

  // ---- S7: out = o_heads @ Wo ----
  for (int task = blk; task < 512; task += nb) {
    int cb = task & 15, ky = task >> 4;
    matvec_body(o_heads, E_, Wo, out, E_, cb << 7, ky, t);
  }
}

extern "C" void kernel_launch(void* const* d_in, const int* in_sizes, int n_in,
                              void* d_out, int out_size, void* d_ws, size_t ws_size,
                              hipStream_t stream)
{
  const float* x    = (const float*)d_in[0];
  const float* ckvc = (const float*)d_in[1];
  const float* krc  = (const float*)d_in[2];
  const float* Wdq  = (const float*)d_in[3];
  const float* Wuq  = (const float*)d_in[4];
  const float* Wqr  = (const float*)d_in[5];
  const float* Wdkv = (const float*)d_in[6];
  const float* Wkr  = (const float*)d_in[7];
  const float* FU   = (const float*)d_in[8];
  const float* Wo   = (const float*)d_in[9];
  float* out = (float*)d_out;
  char* ws = (char*)d_ws;

  // Zero the monotonic barrier counter each call; everything else the kernel
  // zeroes itself in S0.
  hipMemsetAsync(ws + SYNC_OFF, 0, 128, stream);
  mega_kernel<<<dim3(NBLK), dim3(256), 0, stream>>>(
      x, ckvc, krc, Wdq, Wuq, Wqr, Wdkv, Wkr, FU, Wo, out, ws);
}

// Round 10
// 83.982 us; speedup vs baseline: 7.5098x; 4.1747x over previous
//
#include <hip/hip_runtime.h>
#include <hip/hip_bf16.h>

#define B_ 8
#define SPREV 4095
#define S_ 4096
#define E_ 2048
#define H_ 16
#define HD_ 128
#define LOW_ 512
#define NCH 64      // attention s-chunks per batch
#define CHK 64      // positions per chunk

typedef short s8v __attribute__((ext_vector_type(8)));
typedef float f4v __attribute__((ext_vector_type(4)));

__device__ __forceinline__ short f2bf_s(float f) {
  return (short)__bfloat16_as_ushort(__float2bfloat16(f));
}
__device__ __forceinline__ float bf2f(unsigned short h) {
  union { unsigned u; float f; } v; v.u = ((unsigned)h) << 16;
  return v.f;
}

// Zero all accumulation targets + build rope cos/sin table tab2[s][j] (float2).
// grid 1024 x 256 -> i in [0, 262144)
__global__ __launch_bounds__(256) void init_kernel(float* __restrict__ ws_pre,
                                                   float* __restrict__ out,
                                                   float2* __restrict__ tab2) {
  int i = blockIdx.x * 256 + threadIdx.x;
  if (i < 55296) ws_pre[i] = 0.f;           // Cq,Qc,qr_pre,ckvn,krn,o_heads
  else if (i < 71680) out[i - 55296] = 0.f;
  int s = i >> 6, j = i & 63;               // [s][j] layout: rope loads coalesce
  float invf = powf(10000.0f, -(float)j * (1.0f / 64.0f));
  float sn, cs; sincosf((float)s * invf, &sn, &cs);
  tab2[i] = make_float2(cs, sn);
}

// out[b][n] += sum_k x[b][k] * W[k][n], k in [k0, k0+32). Up to 3 column
// segments (separate W/out), each N a multiple of 128. atomicAdd into out.
__global__ __launch_bounds__(128) void matvec8(
    const float* __restrict__ x, int K,
    const float* __restrict__ W0, int N0, float* __restrict__ o0,
    const float* __restrict__ W1, int N1, float* __restrict__ o1,
    const float* __restrict__ W2, int N2, float* __restrict__ o2)
{
  int cb = blockIdx.x;
  int nb0 = N0 >> 7, nb1 = N1 >> 7;
  const float* W; float* o; int N, colbase;
  if (cb < nb0)            { W = W0; o = o0; N = N0; colbase = cb << 7; }
  else if (cb < nb0 + nb1) { W = W1; o = o1; N = N1; colbase = (cb - nb0) << 7; }
  else                     { W = W2; o = o2; N = N2; colbase = (cb - nb0 - nb1) << 7; }
  int col = colbase + threadIdx.x;
  int k0 = blockIdx.y * 32;
  float acc[B_];
  #pragma unroll
  for (int b = 0; b < B_; ++b) acc[b] = 0.f;
  const float* Wp = W + (size_t)k0 * N + col;
  #pragma unroll 8
  for (int k = 0; k < 32; ++k) {
    float wv = Wp[(size_t)k * N];
    #pragma unroll
    for (int b = 0; b < B_; ++b)
      acc[b] = fmaf(x[b * K + k0 + k], wv, acc[b]);   // uniform -> s_load
  }
  #pragma unroll
  for (int b = 0; b < B_; ++b) atomicAdd(&o[b * N + col], acc[b]);
}

// qeff[b,h,l] = sum_d FU[l, h*128+d] * Qc[b, h*128+d]; block = (h*4+lq, b),
// 256 thr = 16 groups x 16 lanes, 128 l's per block. 512 blocks total.
__global__ __launch_bounds__(256) void qeff_kernel(
    const float* __restrict__ Qc, const float* __restrict__ FU,
    unsigned short* __restrict__ qeff)
{
  int bx = blockIdx.x, b = blockIdx.y, t = threadIdx.x;
  int h = bx >> 2, lq = bx & 3;
  int g = t >> 4, li = t & 15;
  __shared__ float qs[HD_];
  if (t < 128) qs[t] = Qc[b * E_ + h * HD_ + t];
  __syncthreads();
  f4v q0 = *(const f4v*)&qs[li * 8];
  f4v q1 = *(const f4v*)&qs[li * 8 + 4];
  #pragma unroll 2
  for (int p = 0; p < 8; ++p) {
    int l = lq * 128 + p * 16 + g;
    const f4v* w4 = (const f4v*)(FU + (size_t)l * (2 * E_) + h * HD_ + li * 8);
    f4v w0 = w4[0], w1 = w4[1];
    float a = w0[0]*q0[0] + w0[1]*q0[1] + w0[2]*q0[2] + w0[3]*q0[3]
            + w1[0]*q1[0] + w1[1]*q1[1] + w1[2]*q1[2] + w1[3]*q1[3];
    a += __shfl_xor(a, 1); a += __shfl_xor(a, 2);
    a += __shfl_xor(a, 4); a += __shfl_xor(a, 8);
    if (li == 0) qeff[(size_t)(b * H_ + h) * LOW_ + l] = (unsigned short)f2bf_s(a);
  }
}

// Flash-decode in latent space, one (b, 64-position chunk) per block.
// Phase A: S[16h][64s] = qeff . ckv^T via MFMA; PLUS inline rope score per s
// (kg-partitioned j-dot + shfl reduce). Phase B: chunk softmax. Phase C: PV.
__global__ __launch_bounds__(256) void attn_kernel(
    const float* __restrict__ ckv_cache, const float* __restrict__ ckv_new,
    const unsigned short* __restrict__ qeff,
    const float* __restrict__ kr_cache, const float* __restrict__ kr_new,
    const float* __restrict__ qr_pre, const float2* __restrict__ tab2,
    unsigned short* __restrict__ acc_part, float* __restrict__ m_part,
    float* __restrict__ l_part)
{
  int chunk = blockIdx.x, b = blockIdx.y;
  int tid = threadIdx.x;
  int w = tid >> 6, lane = tid & 63;
  int kg = lane >> 4, l16 = lane & 15;
  __shared__ float S_lds[16 * 64];          // swizzled: h*64 + (s ^ ((h&7)<<2))
  __shared__ unsigned short P_lds[16 * 64]; // swizzled: h*64 + (s ^ ((h&7)<<3))
  __shared__ float qr_sh[128];
  __shared__ float rope_lds[64];

  // qr rotated at position 4095 (once per block; numerics match reference)
  if (tid < 64) {
    float invf = powf(10000.0f, -(float)tid * (1.0f / 64.0f));
    float x1 = qr_pre[b * HD_ + tid], x2 = qr_pre[b * HD_ + 64 + tid];
    float sn, cs; sincosf(4095.0f * invf, &sn, &cs);
    qr_sh[tid]      = x1 * cs - x2 * sn;
    qr_sh[64 + tid] = x1 * sn + x2 * cs;
  }
  __syncthreads();

  { // ---- phase A: QK^T MFMA + inline rope dot ----
    int s_loc = w * 16 + l16;
    int s = chunk * CHK + s_loc;
    const float* crow = (s == S_ - 1) ? (ckv_new + b * LOW_)
                                      : (ckv_cache + ((size_t)b * SPREV + s) * LOW_);
    f4v acc = {0.f, 0.f, 0.f, 0.f};
    const s8v* qf = (const s8v*)(qeff + (size_t)(b * H_ + l16) * LOW_);
    #pragma unroll
    for (int kt = 0; kt < 16; ++kt) {
      s8v a = qf[kt * 4 + kg];
      const float* cp = crow + kt * 32 + kg * 8;
      f4v c0 = *(const f4v*)cp;
      f4v c1 = *(const f4v*)(cp + 4);
      s8v bv;
      bv[0]=f2bf_s(c0[0]); bv[1]=f2bf_s(c0[1]); bv[2]=f2bf_s(c0[2]); bv[3]=f2bf_s(c0[3]);
      bv[4]=f2bf_s(c1[0]); bv[5]=f2bf_s(c1[1]); bv[6]=f2bf_s(c1[2]); bv[7]=f2bf_s(c1[3]);
      acc = __builtin_amdgcn_mfma_f32_16x16x32_bf16(a, bv, acc, 0, 0, 0);
    }
    #pragma unroll
    for (int r = 0; r < 4; ++r) {
      int h = kg * 4 + r;
      S_lds[h * 64 + (s_loc ^ ((h & 7) << 2))] = acc[r];
    }
    // rope score for this s: j-range kg*16..+15, reduce across kg via shfl
    const float* krp = (s == S_ - 1) ? (kr_new + b * HD_)
                                     : (kr_cache + ((size_t)b * SPREV + s) * HD_);
    float rdot = 0.f;
    #pragma unroll
    for (int q = 0; q < 4; ++q) {
      int j = kg * 16 + q * 4;
      f4v x1 = *(const f4v*)&krp[j];
      f4v x2 = *(const f4v*)&krp[64 + j];
      f4v qa = *(const f4v*)&qr_sh[j];
      f4v qb = *(const f4v*)&qr_sh[64 + j];
      const float2* tp = &tab2[(size_t)s * 64 + j];
      #pragma unroll
      for (int k = 0; k < 4; ++k) {
        float2 cs2 = tp[k];
        rdot += qa[k] * (x1[k] * cs2.x - x2[k] * cs2.y)
              + qb[k] * (x1[k] * cs2.y + x2[k] * cs2.x);
      }
    }
    rdot += __shfl_xor(rdot, 16);
    rdot += __shfl_xor(rdot, 32);
    if (kg == 0) rope_lds[s_loc] = rdot;
  }
  __syncthreads();

  if (w == 0) { // ---- phase B: lane = part*16 + h; part owns 16 s ----
    int h = l16, part = kg;
    float v[16];
    #pragma unroll
    for (int jj = 0; jj < 4; ++jj) {
      int sb = part * 16 + jj * 4;
      f4v sv = *(const f4v*)&S_lds[h * 64 + (sb ^ ((h & 7) << 2))];
      f4v rv = *(const f4v*)&rope_lds[sb];
      #pragma unroll
      for (int q = 0; q < 4; ++q) v[jj * 4 + q] = (sv[q] + rv[q]) * 0.0625f;
    }
    float m = v[0];
    #pragma unroll
    for (int j = 1; j < 16; ++j) m = fmaxf(m, v[j]);
    m = fmaxf(m, __shfl_xor(m, 16));
    m = fmaxf(m, __shfl_xor(m, 32));
    float lsum = 0.f;
    #pragma unroll
    for (int j = 0; j < 16; ++j) { v[j] = expf(v[j] - m); lsum += v[j]; }
    lsum += __shfl_xor(lsum, 16);
    lsum += __shfl_xor(lsum, 32);
    #pragma unroll
    for (int jj = 0; jj < 8; ++jj) {
      int sb = part * 16 + jj * 2;
      unsigned pk = (unsigned)(unsigned short)f2bf_s(v[jj*2]) |
                    ((unsigned)(unsigned short)f2bf_s(v[jj*2+1]) << 16);
      *(unsigned*)&P_lds[h * 64 + (sb ^ ((h & 7) << 3))] = pk;
    }
    if (part == 0) {
      int idx = (b * NCH + chunk) * H_ + h;
      m_part[idx] = m;
      l_part[idx] = lsum;
    }
  }
  __syncthreads();

  { // ---- phase C: wave w owns l in [w*128, w*128+128) ----
    s8v pa[2];
    const float* rp[2][8];
    #pragma unroll
    for (int kt = 0; kt < 2; ++kt) {
      int so = kt * 32 + kg * 8;
      pa[kt] = *(const s8v*)&P_lds[l16 * 64 + (so ^ ((l16 & 7) << 3))];
      #pragma unroll
      for (int i = 0; i < 8; ++i) {
        int s = chunk * CHK + so + i;
        rp[kt][i] = (s == S_ - 1) ? (ckv_new + b * LOW_)
                                  : (ckv_cache + ((size_t)b * SPREV + s) * LOW_);
      }
    }
    f4v oa[8];
    #pragma unroll
    for (int nt = 0; nt < 8; ++nt) oa[nt] = {0.f, 0.f, 0.f, 0.f};
    #pragma unroll
    for (int nt = 0; nt < 8; ++nt) {
      int l = w * 128 + nt * 16 + l16;
      #pragma unroll
      for (int kt = 0; kt < 2; ++kt) {
        s8v bv;
        #pragma unroll
        for (int i = 0; i < 8; ++i) bv[i] = (short)f2bf_s(rp[kt][i][l]);
        oa[nt] = __builtin_amdgcn_mfma_f32_16x16x32_bf16(pa[kt], bv, oa[nt], 0, 0, 0);
      }
    }
    size_t base = (size_t)(b * NCH + chunk) * H_;
    #pragma unroll
    for (int nt = 0; nt < 8; ++nt) {
      int l = w * 128 + nt * 16 + l16;
      #pragma unroll
      for (int r = 0; r < 4; ++r) {
        int h = kg * 4 + r;
        acc_part[(base + h) * LOW_ + l] = (unsigned short)f2bf_s(oa[nt][r]);
      }
    }
  }
}

// Fused combine + project. Block = (h, b, lz): builds wl for 64 l's in LDS
// (all 64 chunks), then projects through FU V-half, atomicAdd o_heads.
// grid (16,8,8) x 128 thr.
__global__ __launch_bounds__(128) void reduce_proj_kernel(
    const float* __restrict__ m_part, const float* __restrict__ l_part,
    const unsigned short* __restrict__ acc_part, const float* __restrict__ FU,
    float* __restrict__ o_heads)
{
  int h = blockIdx.x, b = blockIdx.y, lz = blockIdx.z, t = threadIdx.x;
  __shared__ float wls[NCH];
  __shared__ float Linv_s;
  __shared__ float pa0[128], pa1[128];
  __shared__ float wl_sh[64];
  if (t < 64) {
    float mc = m_part[(b * NCH + t) * H_ + h];
    float M = mc;
    #pragma unroll
    for (int d = 1; d < 64; d <<= 1) M = fmaxf(M, __shfl_xor(M, d));
    float wc = expf(mc - M);
    float L = l_part[(b * NCH + t) * H_ + h] * wc;
    #pragma unroll
    for (int d = 1; d < 64; d <<= 1) L += __shfl_xor(L, d);
    wls[t] = wc;
    if (t == 0) Linv_s = 1.0f / L;
  }
  __syncthreads();
  // stage 2: thread t = (chunk-quarter ch, l-pair p)
  {
    int p = t & 31, ch = t >> 5;
    int l0 = lz * 64 + p * 2;
    float a0 = 0.f, a1 = 0.f;
    const unsigned short* ap =
        acc_part + ((size_t)(b * NCH + ch * 16) * H_ + h) * LOW_ + l0;
    #pragma unroll 4
    for (int c = 0; c < 16; ++c) {
      unsigned pk = *(const unsigned*)(ap + (size_t)c * H_ * LOW_);
      float wc = wls[ch * 16 + c];
      a0 = fmaf(bf2f((unsigned short)(pk & 0xffffu)), wc, a0);
      a1 = fmaf(bf2f((unsigned short)(pk >> 16)),     wc, a1);
    }
    pa0[t] = a0; pa1[t] = a1;
  }
  __syncthreads();
  if (t < 32) {
    float inv = Linv_s;
    float s0 = pa0[t] + pa0[t + 32] + pa0[t + 64] + pa0[t + 96];
    float s1 = pa1[t] + pa1[t + 32] + pa1[t + 64] + pa1[t + 96];
    wl_sh[t * 2]     = s0 * inv;
    wl_sh[t * 2 + 1] = s1 * inv;
  }
  __syncthreads();
  // stage 3: project 64 l's x 128 d
  {
    float a = 0.f;
    const float* fp = FU + (size_t)(lz * 64) * (2 * E_) + E_ + h * HD_ + t;
    #pragma unroll 4
    for (int l = 0; l < 64; ++l)
      a = fmaf(wl_sh[l], fp[(size_t)l * (2 * E_)], a);
    atomicAdd(&o_heads[(b * H_ + h) * HD_ + t], a);
  }
}

extern "C" void kernel_launch(void* const* d_in, const int* in_sizes, int n_in,
                              void* d_out, int out_size, void* d_ws, size_t ws_size,
                              hipStream_t stream)
{
  const float* x    = (const float*)d_in[0];
  const float* ckvc = (const float*)d_in[1];
  const float* krc  = (const float*)d_in[2];
  const float* Wdq  = (const float*)d_in[3];
  const float* Wuq  = (const float*)d_in[4];
  const float* Wqr  = (const float*)d_in[5];
  const float* Wdkv = (const float*)d_in[6];
  const float* Wkr  = (const float*)d_in[7];
  const float* FU   = (const float*)d_in[8];
  const float* Wo   = (const float*)d_in[9];
  float* out = (float*)d_out;

  char* ws = (char*)d_ws;
  // zeroed prefix (55296 floats):
  float* Cq             = (float*)(ws + 0);        // 65536 B
  float* Qc             = (float*)(ws + 65536);    // 65536 B
  float* qr_pre         = (float*)(ws + 131072);   // 4096 B
  float* ckvn           = (float*)(ws + 135168);   // 16384 B
  float* krn            = (float*)(ws + 151552);   // 4096 B
  float* o_heads        = (float*)(ws + 155648);   // 65536 B  [prefix end 221184]
  unsigned short* qeff  = (unsigned short*)(ws + 221184);  // 131072 B
  float* m_part         = (float*)(ws + 352256);   // 32768 B
  float* l_part         = (float*)(ws + 385024);   // 32768 B
  unsigned short* accp  = (unsigned short*)(ws + 417792);  // 8388608 B
  float2* tab2          = (float2*)(ws + 8806400); // 2097152 B (total ~10.9 MB)

  // Zero all atomic targets + build rope table
  init_kernel<<<1024, 256, 0, stream>>>((float*)ws, out, tab2);

  // Cq = x@Wdq ; ckv_new = x@Wdkv ; kr_new = x@Wkr
  matvec8<<<dim3(21, 64), 128, 0, stream>>>(x, E_, Wdq, E_, Cq,
                                            Wdkv, LOW_, ckvn, Wkr, HD_, krn);
  // Qc = Cq@Wuq ; qr_pre = Cq@Wqr
  matvec8<<<dim3(17, 64), 128, 0, stream>>>(Cq, E_, Wuq, E_, Qc,
                                            Wqr, HD_, qr_pre,
                                            (const float*)nullptr, 0, (float*)nullptr);
  qeff_kernel<<<dim3(64, 8), 256, 0, stream>>>(Qc, FU, qeff);
  attn_kernel<<<dim3(64, 8), 256, 0, stream>>>(ckvc, ckvn, qeff, krc, krn,
                                               qr_pre, tab2, accp, m_part, l_part);
  reduce_proj_kernel<<<dim3(16, 8, 8), 128, 0, stream>>>(m_part, l_part, accp,
                                                         FU, o_heads);
  // out = o_heads @ Wo
  matvec8<<<dim3(16, 64), 128, 0, stream>>>(o_heads, E_, Wo, E_, out,
                                            (const float*)nullptr, 0, (float*)nullptr,
                                            (const float*)nullptr, 0, (float*)nullptr);
}